// Round 1
// baseline (106.894 us; speedup 1.0000x reference)
//
#include <hip/hip_runtime.h>
#include <stdint.h>

#define NROWS 8192
#define DDIM 256
#define NPIDS 5532
#define NCQ 5000
#define LCOLS 10532            // NPIDS + NCQ
#define IGNORE_IDX 5554
#define BM 128
#define BN 128
#define NT 83                  // ceil(10532/128)
#define LPAD (NT * BN)         // 10624
#define NSPLIT 4
#define TPS 21                 // ceil(83/4)
#define OIM_SCALE 30.0f
#define LOG2E 1.4426950408889634f
#define LN2f 0.6931471805599453f

using f32x4 = __attribute__((ext_vector_type(4))) float;
using bf16x8 = __attribute__((ext_vector_type(8))) __bf16;
using ushort8 = __attribute__((ext_vector_type(8))) unsigned short;

// ws layout (bytes)
#define WS_INSWZ 0u            // 8192*256*2   = 4,194,304
#define WS_BANK 4194304u       // 10624*256*2  = 5,439,488
#define WS_RSE 9633792u        // 10624*4      = 42,496
#define WS_PARTS 9676288u      // 8*8192*4     = 262,144
#define WS_RLOGIT 9938432u     // 8192*4       = 32,768
#define WS_NEED 9971200u

__device__ __forceinline__ unsigned short f2bf(float f) {
  union { float f; uint32_t u; } v; v.f = f;
  uint32_t u = v.u;
  uint32_t r = (u + 0x7FFFu + ((u >> 16) & 1u)) >> 16;  // RNE
  return (unsigned short)r;
}

__device__ __forceinline__ void async16(const void* g, void* l) {
  __builtin_amdgcn_global_load_lds(
      (const __attribute__((address_space(1))) uint32_t*)g,
      (__attribute__((address_space(3))) uint32_t*)l, 16, 0, 0);
}

// ---------------------------------------------------------------------------
// prep: f32 -> bf16 conversion of inputs and bank (lut||cq, zero pad),
// stored PRE-XOR-SWIZZLED: ws[r][c] = M[r][c ^ ((r&7)<<3)]  (8-elem granules)
// so a LINEAR global_load_lds into a [rows][256] LDS tile lands swizzled.
// Also rse[j] = 30 * rel[j] * log2(e), 0 in the pad.
// ---------------------------------------------------------------------------
__global__ void prep_kernel(const float* __restrict__ inputs,
                            const float* __restrict__ lut,
                            const float* __restrict__ cq,
                            const float* __restrict__ rel,
                            unsigned short* __restrict__ in_swz,
                            unsigned short* __restrict__ bank_swz,
                            float* __restrict__ rse) {
  const int GIN = NROWS * (DDIM / 8);   // 262144 granules
  const int GBK = LPAD * (DDIM / 8);    // 339968 granules
  const int total = GIN + GBK + LPAD;
  for (int g = blockIdx.x * blockDim.x + threadIdx.x; g < total;
       g += gridDim.x * blockDim.x) {
    if (g < GIN + GBK) {
      const int base = (g < GIN) ? g : (g - GIN);
      const int r = base >> 5;          // row
      const int c8 = base & 31;         // output granule within row
      const int sc8 = c8 ^ (r & 7);     // swizzled source granule
      const float* src = nullptr;
      unsigned short* dst;
      bool zero = false;
      if (g < GIN) {
        src = inputs + r * DDIM + sc8 * 8;
        dst = in_swz + r * DDIM + c8 * 8;
      } else {
        dst = bank_swz + r * DDIM + c8 * 8;
        if (r < NPIDS) src = lut + r * DDIM + sc8 * 8;
        else if (r < LCOLS) src = cq + (r - NPIDS) * DDIM + sc8 * 8;
        else zero = true;
      }
      ushort8 o = {0, 0, 0, 0, 0, 0, 0, 0};
      if (!zero) {
        const f32x4* s4 = (const f32x4*)src;
        f32x4 v0 = s4[0], v1 = s4[1];
        o[0] = f2bf(v0[0]); o[1] = f2bf(v0[1]);
        o[2] = f2bf(v0[2]); o[3] = f2bf(v0[3]);
        o[4] = f2bf(v1[0]); o[5] = f2bf(v1[1]);
        o[6] = f2bf(v1[2]); o[7] = f2bf(v1[3]);
      }
      *(ushort8*)dst = o;
    } else {
      const int j = g - GIN - GBK;
      rse[j] = (j < LCOLS) ? OIM_SCALE * LOG2E * rel[j] : 0.0f;
    }
  }
}

// ---------------------------------------------------------------------------
// main: fused GEMM + sum-of-exp per row.
// grid (64 row tiles, 4 L-splits), 256 threads = 4 waves (2x2), 128x128 tile.
// LDS: A[128][256] bf16 (64KB, staged once) + B[128][256] bf16 (64KB/tile).
// Per wave 64x64 output = 4x4 frags of mfma_f32_16x16x32_bf16, K=256 (8 ksteps).
// Epilogue per tile: se[mi][r] += exp2(acc * rse[col]) (masked col<LCOLS).
// Next-tile B staging issued BEFORE the epilogue (latency hides under exp).
// ---------------------------------------------------------------------------
__global__ __launch_bounds__(256) void oim_main_kernel(
    const unsigned short* __restrict__ in_swz,
    const unsigned short* __restrict__ bank_swz,
    const float* __restrict__ rse,
    float* __restrict__ parts) {
  extern __shared__ char smem[];
  char* As = smem;            // 65536 B
  char* Bs = smem + 65536;    // 65536 B
  const int tid = threadIdx.x;
  const int lane = tid & 63;
  const int wv = tid >> 6;
  const int wrow = wv >> 1;   // 0..1
  const int wcol = wv & 1;    // 0..1
  const int q = lane & 15;
  const int h = lane >> 4;    // 0..3
  const int xorb = (lane & 7) << 4;

  const int bm = blockIdx.x;
  const int sp = blockIdx.y;
  const int t0 = sp * TPS;
  const int t1 = min(NT, t0 + TPS);

  // stage A (once)
  {
    const char* srcA = (const char*)in_swz + (size_t)bm * (BM * DDIM * 2);
#pragma unroll
    for (int i = 0; i < 16; ++i) {
      const int off = i * 4096 + tid * 16;
      async16(srcA + off, As + off);
    }
  }
  // stage first B tile
  {
    const char* srcB = (const char*)bank_swz + (size_t)t0 * (BN * DDIM * 2);
#pragma unroll
    for (int i = 0; i < 16; ++i) {
      const int off = i * 4096 + tid * 16;
      async16(srcB + off, Bs + off);
    }
  }

  const f32x4 vzero = {0.f, 0.f, 0.f, 0.f};
  f32x4 acc[4][4];
  float se[4][4];
#pragma unroll
  for (int a = 0; a < 4; ++a)
#pragma unroll
    for (int b = 0; b < 4; ++b) { acc[a][b] = vzero; se[a][b] = 0.f; }

  const int arow0 = wrow * 64 + q;   // A row within tile for this lane
  const int brow0 = wcol * 64 + q;   // bank row (output col) within tile

  for (int t = t0; t < t1; ++t) {
    __syncthreads();  // staged A/B ready (compiler drains vmcnt before barrier)
#pragma unroll
    for (int kk = 0; kk < 8; ++kk) {
      const int ko = ((kk * 64 + h * 16) ^ xorb);  // swizzled k-offset (bytes)
      bf16x8 aF[4], bF[4];
#pragma unroll
      for (int mi = 0; mi < 4; ++mi)
        aF[mi] = *(const bf16x8*)(As + (arow0 + mi * 16) * 512 + ko);
#pragma unroll
      for (int ni = 0; ni < 4; ++ni)
        bF[ni] = *(const bf16x8*)(Bs + (brow0 + ni * 16) * 512 + ko);
#pragma unroll
      for (int mi = 0; mi < 4; ++mi)
#pragma unroll
        for (int ni = 0; ni < 4; ++ni)
          acc[mi][ni] = __builtin_amdgcn_mfma_f32_16x16x32_bf16(
              aF[mi], bF[ni], acc[mi][ni], 0, 0, 0);
    }
    __syncthreads();  // all waves done reading Bs
    if (t + 1 < t1) { // issue next B staging; latency hides under epilogue
      const char* srcB =
          (const char*)bank_swz + (size_t)(t + 1) * (BN * DDIM * 2);
#pragma unroll
      for (int i = 0; i < 16; ++i) {
        const int off = i * 4096 + tid * 16;
        async16(srcB + off, Bs + off);
      }
    }
    // epilogue: exp2 accumulate
    const int colb = t * BN + wcol * 64 + q;
#pragma unroll
    for (int ni = 0; ni < 4; ++ni) {
      const int col = colb + ni * 16;
      const float rv = rse[col];        // rse has LPAD entries; 0 in pad
      const bool ok = col < LCOLS;
#pragma unroll
      for (int mi = 0; mi < 4; ++mi) {
#pragma unroll
        for (int r = 0; r < 4; ++r) {
          const float e = exp2f(acc[mi][ni][r] * rv);
          se[mi][r] += ok ? e : 0.0f;
        }
        acc[mi][ni] = vzero;
      }
    }
  }

  // reduce across the 16 column-lanes of each row group
#pragma unroll
  for (int mi = 0; mi < 4; ++mi)
#pragma unroll
    for (int r = 0; r < 4; ++r) {
      float v = se[mi][r];
      v += __shfl_xor(v, 1);
      v += __shfl_xor(v, 2);
      v += __shfl_xor(v, 4);
      v += __shfl_xor(v, 8);
      se[mi][r] = v;
    }
  if (q == 0) {
    const int part = sp * 2 + wcol;  // deterministic partial slot
#pragma unroll
    for (int mi = 0; mi < 4; ++mi)
#pragma unroll
      for (int r = 0; r < 4; ++r) {
        const int row = bm * BM + wrow * 64 + mi * 16 + h * 4 + r;
        parts[part * NROWS + row] = se[mi][r];
      }
  }
}

// ---------------------------------------------------------------------------
// exact fp32 label logit: one wave per row, gather bank row by label.
// ---------------------------------------------------------------------------
__global__ void label_logit_kernel(const float* __restrict__ inputs,
                                   const int* __restrict__ label,
                                   const float* __restrict__ lut,
                                   const float* __restrict__ cq,
                                   const float* __restrict__ rel,
                                   float* __restrict__ rowlogit) {
  const int lane = threadIdx.x & 63;
  const int wv = threadIdx.x >> 6;
  const int row = blockIdx.x * 4 + wv;
  if (row >= NROWS) return;
  const int l = label[row];
  float out = 0.0f;
  if (l != IGNORE_IDX && l >= 0 && l < LCOLS) {
    const float* bk = (l < NPIDS) ? (lut + (size_t)l * DDIM)
                                  : (cq + (size_t)(l - NPIDS) * DDIM);
    f32x4 a = *(const f32x4*)(inputs + (size_t)row * DDIM + lane * 4);
    f32x4 b = *(const f32x4*)(bk + lane * 4);
    float d = a[0] * b[0] + a[1] * b[1] + a[2] * b[2] + a[3] * b[3];
#pragma unroll
    for (int m = 1; m < 64; m <<= 1) d += __shfl_xor(d, m);
    out = OIM_SCALE * rel[l] * d;
  }
  if (lane == 0) rowlogit[row] = out;
}

// ---------------------------------------------------------------------------
// finalize: loss = sum_valid(ln2*log2(sum_exp) - label_logit) / count
// ---------------------------------------------------------------------------
__global__ void finalize_kernel(const float* __restrict__ parts,
                                const float* __restrict__ rowlogit,
                                const int* __restrict__ label,
                                float* __restrict__ out) {
  const int tid = threadIdx.x;
  float s = 0.0f, c = 0.0f;
  for (int r = tid; r < NROWS; r += 256) {
    if (label[r] != IGNORE_IDX) {
      float tot = 0.0f;
#pragma unroll
      for (int p = 0; p < 2 * NSPLIT; ++p) tot += parts[p * NROWS + r];
      s += LN2f * log2f(tot) - rowlogit[r];
      c += 1.0f;
    }
  }
#pragma unroll
  for (int m = 1; m < 64; m <<= 1) {
    s += __shfl_xor(s, m);
    c += __shfl_xor(c, m);
  }
  __shared__ float ss[4], sc[4];
  const int wv = tid >> 6, lane = tid & 63;
  if (lane == 0) { ss[wv] = s; sc[wv] = c; }
  __syncthreads();
  if (tid == 0) {
    const float S = ss[0] + ss[1] + ss[2] + ss[3];
    const float C = sc[0] + sc[1] + sc[2] + sc[3];
    out[0] = S / fmaxf(C, 1.0f);
  }
}

extern "C" void kernel_launch(void* const* d_in, const int* in_sizes, int n_in,
                              void* d_out, int out_size, void* d_ws,
                              size_t ws_size, hipStream_t stream) {
  const float* inputs = (const float*)d_in[0];
  const int* label = (const int*)d_in[1];
  // d_in[2] = ious (unused by the reference loss)
  const float* lut = (const float*)d_in[3];
  const float* cq = (const float*)d_in[4];
  const float* rel = (const float*)d_in[5];
  float* out = (float*)d_out;
  char* ws = (char*)d_ws;
  if (ws_size < WS_NEED) return;

  unsigned short* in_swz = (unsigned short*)(ws + WS_INSWZ);
  unsigned short* bank_swz = (unsigned short*)(ws + WS_BANK);
  float* rse = (float*)(ws + WS_RSE);
  float* parts = (float*)(ws + WS_PARTS);
  float* rowlogit = (float*)(ws + WS_RLOGIT);

  hipFuncSetAttribute((const void*)oim_main_kernel,
                      hipFuncAttributeMaxDynamicSharedMemorySize, 131072);

  prep_kernel<<<dim3(1024), dim3(256), 0, stream>>>(inputs, lut, cq, rel,
                                                    in_swz, bank_swz, rse);
  oim_main_kernel<<<dim3(64, NSPLIT), dim3(256), 131072, stream>>>(
      in_swz, bank_swz, rse, parts);
  label_logit_kernel<<<dim3(2048), dim3(256), 0, stream>>>(inputs, label, lut,
                                                           cq, rel, rowlogit);
  finalize_kernel<<<dim3(1), dim3(256), 0, stream>>>(parts, rowlogit, label,
                                                     out);
}

// Round 2
// 85.192 us; speedup vs baseline: 1.2547x; 1.2547x over previous
//
#include <hip/hip_runtime.h>
#include <stdint.h>

#define NROWS 8192
#define DDIM 256
#define NPIDS 5532
#define NCQ 5000
#define LCOLS 10532            // NPIDS + NCQ
#define IGNORE_IDX 5554
#define BM 128
#define BN 128
#define NT 83                  // ceil(10532/128)
#define LPAD (NT * BN)         // 10624
#define NSPLIT 8
#define NPARTS (NSPLIT * 2)    // 16 partial slots per row
#define PADCOLS (LPAD - LCOLS) // 92, each contributes exp2(0)=1 exactly
#define OIM_SCALE 30.0f
#define LOG2E 1.4426950408889634f
#define LN2f 0.6931471805599453f

using f32x4 = __attribute__((ext_vector_type(4))) float;
using bf16x8 = __attribute__((ext_vector_type(8))) __bf16;
using ushort8 = __attribute__((ext_vector_type(8))) unsigned short;

// ws layout (bytes)
#define WS_INBF 0u             // 8192*256*2   = 4,194,304 (plain bf16)
#define WS_BANK 4194304u       // 10624*256*2  = 5,439,488 (swizzled bf16)
#define WS_RSE 9633792u        // 10624*4      = 42,496
#define WS_PARTS 9676288u      // 16*8192*4    = 524,288
#define WS_RLOGIT 10200576u    // 8192*4       = 32,768
#define WS_BLK 10233344u       // 32*2*4       = 256
#define WS_NEED 10233600u

__device__ __forceinline__ unsigned short f2bf(float f) {
  union { float f; uint32_t u; } v; v.f = f;
  uint32_t u = v.u;
  uint32_t r = (u + 0x7FFFu + ((u >> 16) & 1u)) >> 16;  // RNE
  return (unsigned short)r;
}

__device__ __forceinline__ void async16(const void* g, void* l) {
  __builtin_amdgcn_global_load_lds(
      (const __attribute__((address_space(1))) uint32_t*)g,
      (__attribute__((address_space(3))) uint32_t*)l, 16, 0, 0);
}

// ---------------------------------------------------------------------------
// prep: inputs -> plain bf16 (A is consumed from global into register frags,
// 16B granules at [row][kk*32 + h*8] are contiguous -> no swizzle needed).
// bank (lut||cq, zero pad) -> bf16 PRE-XOR-SWIZZLED in 16B granules:
// ws[r][c] = M[r][c ^ (r&7)] so a LINEAR global_load_lds lands swizzled.
// rse[j] = 30 * rel[j] * log2(e), 0 in the pad.
// ---------------------------------------------------------------------------
__global__ void prep_kernel(const float* __restrict__ inputs,
                            const float* __restrict__ lut,
                            const float* __restrict__ cq,
                            const float* __restrict__ rel,
                            unsigned short* __restrict__ in_bf,
                            unsigned short* __restrict__ bank_swz,
                            float* __restrict__ rse) {
  const int GIN = NROWS * (DDIM / 8);   // 262144 granules
  const int GBK = LPAD * (DDIM / 8);    // 339968 granules
  const int total = GIN + GBK + LPAD;
  for (int g = blockIdx.x * blockDim.x + threadIdx.x; g < total;
       g += gridDim.x * blockDim.x) {
    if (g < GIN + GBK) {
      const int base = (g < GIN) ? g : (g - GIN);
      const int r = base >> 5;          // row
      const int c8 = base & 31;         // output granule within row
      const float* src = nullptr;
      unsigned short* dst;
      bool zero = false;
      if (g < GIN) {
        src = inputs + r * DDIM + c8 * 8;          // A: no swizzle
        dst = in_bf + r * DDIM + c8 * 8;
      } else {
        const int sc8 = c8 ^ (r & 7);              // B: swizzled source
        dst = bank_swz + r * DDIM + c8 * 8;
        if (r < NPIDS) src = lut + r * DDIM + sc8 * 8;
        else if (r < LCOLS) src = cq + (r - NPIDS) * DDIM + sc8 * 8;
        else zero = true;
      }
      ushort8 o = {0, 0, 0, 0, 0, 0, 0, 0};
      if (!zero) {
        const f32x4* s4 = (const f32x4*)src;
        f32x4 v0 = s4[0], v1 = s4[1];
        o[0] = f2bf(v0[0]); o[1] = f2bf(v0[1]);
        o[2] = f2bf(v0[2]); o[3] = f2bf(v0[3]);
        o[4] = f2bf(v1[0]); o[5] = f2bf(v1[1]);
        o[6] = f2bf(v1[2]); o[7] = f2bf(v1[3]);
      }
      *(ushort8*)dst = o;
    } else {
      const int j = g - GIN - GBK;
      rse[j] = (j < LCOLS) ? OIM_SCALE * LOG2E * rel[j] : 0.0f;
    }
  }
}

// ---------------------------------------------------------------------------
// main: fused GEMM + sum-of-exp per row.
// grid 512 blocks (2/CU), 256 threads = 4 waves (2x2 over a 128x128 tile).
// sp = blockIdx & 7 -> XCD-partitioned column splits (round-robin dispatch):
// each XCD's 64 blocks share one 10-11-tile B slice (L2-resident).
// A: per-wave register fragments (128 VGPRs), loaded once from global.
// B: single 64KB LDS buffer, global_load_lds width-16, next tile issued
//    before the exp epilogue so HBM/L2 latency hides under VALU.
// ds_read addresses: two per-lane bases (kk parity) + offset immediates.
// ---------------------------------------------------------------------------
__global__ __launch_bounds__(256, 2) void oim_main_kernel(
    const unsigned short* __restrict__ in_bf,
    const unsigned short* __restrict__ bank_swz,
    const float* __restrict__ rse,
    float* __restrict__ parts) {
  extern __shared__ char Bs[];  // 65536 B
  const int tid = threadIdx.x;
  const int lane = tid & 63;
  const int wv = tid >> 6;
  const int wrow = wv >> 1;   // 0..1
  const int wcol = wv & 1;    // 0..1
  const int q = lane & 15;
  const int h = lane >> 4;    // 0..3

  const int sp = blockIdx.x & 7;
  const int bm = blockIdx.x >> 3;

  // ---- A fragments -> registers (once) ----
  bf16x8 aR[4][8];
  {
    const unsigned short* ab =
        in_bf + ((size_t)(bm * BM + wrow * 64 + q) * DDIM + h * 8);
#pragma unroll
    for (int mi = 0; mi < 4; ++mi)
#pragma unroll
      for (int kk = 0; kk < 8; ++kk)
        aR[mi][kk] = *(const bf16x8*)(ab + mi * 16 * DDIM + kk * 32);
  }

  // ---- stage first B tile ----
  {
    const char* src = (const char*)bank_swz + (size_t)sp * 65536 + tid * 16;
#pragma unroll
    for (int i = 0; i < 16; ++i)
      async16(src + i * 4096, Bs + tid * 16 + i * 4096);
  }

  // ---- B LDS read bases: addr(kk,ni) = base[kk&1] + (kk>>1)*128 + ni*8192
  const int browB = wcol * 64 + q;
  const int slot0 = (h ^ (q & 7)) << 4;
  const char* b0 = Bs + browB * 512 + slot0;
  const char* b1 = Bs + browB * 512 + (slot0 ^ 64);

  const f32x4 vzero = {0.f, 0.f, 0.f, 0.f};
  f32x4 acc[4][4];
  float se[4][4];
#pragma unroll
  for (int a = 0; a < 4; ++a)
#pragma unroll
    for (int b = 0; b < 4; ++b) se[a][b] = 0.f;

  for (int t = sp; t < NT; t += NSPLIT) {
    __syncthreads();  // staged B ready (compiler drains vmcnt before barrier)
#pragma unroll
    for (int kk = 0; kk < 8; ++kk) {
      const char* bp = (kk & 1) ? b1 : b0;
      const int mo = (kk >> 1) * 128;
      bf16x8 bF[4];
#pragma unroll
      for (int ni = 0; ni < 4; ++ni)
        bF[ni] = *(const bf16x8*)(bp + mo + ni * 8192);
#pragma unroll
      for (int mi = 0; mi < 4; ++mi)
#pragma unroll
        for (int ni = 0; ni < 4; ++ni)
          acc[mi][ni] = __builtin_amdgcn_mfma_f32_16x16x32_bf16(
              aR[mi][kk], bF[ni], (kk == 0) ? vzero : acc[mi][ni], 0, 0, 0);
    }
    __syncthreads();  // all waves done reading Bs
    if (t + NSPLIT < NT) {  // issue next B staging; hides under epilogue
      const char* src =
          (const char*)bank_swz + (size_t)(t + NSPLIT) * 65536 + tid * 16;
#pragma unroll
      for (int i = 0; i < 16; ++i)
        async16(src + i * 4096, Bs + tid * 16 + i * 4096);
    }
    // epilogue: exp2 accumulate (pad cols have rse=0 -> exp2(0)=1, corrected
    // by subtracting PADCOLS in the finalize)
    const int colb = t * BN + wcol * 64 + q;
#pragma unroll
    for (int ni = 0; ni < 4; ++ni) {
      const float rv = rse[colb + ni * 16];
#pragma unroll
      for (int mi = 0; mi < 4; ++mi)
#pragma unroll
        for (int r = 0; r < 4; ++r)
          se[mi][r] += __builtin_amdgcn_exp2f(acc[mi][ni][r] * rv);
    }
  }

  // reduce across the 16 column-lanes (q) of each row group
#pragma unroll
  for (int mi = 0; mi < 4; ++mi)
#pragma unroll
    for (int r = 0; r < 4; ++r) {
      float v = se[mi][r];
      v += __shfl_xor(v, 1);
      v += __shfl_xor(v, 2);
      v += __shfl_xor(v, 4);
      v += __shfl_xor(v, 8);
      se[mi][r] = v;
    }
  if (q == 0) {
    const int part = sp * 2 + wcol;  // deterministic partial slot
#pragma unroll
    for (int mi = 0; mi < 4; ++mi)
#pragma unroll
      for (int r = 0; r < 4; ++r) {
        const int row = bm * BM + wrow * 64 + mi * 16 + h * 4 + r;
        parts[part * NROWS + row] = se[mi][r];
      }
  }
}

// ---------------------------------------------------------------------------
// exact fp32 label logit: one wave per row, gather bank row by label.
// ---------------------------------------------------------------------------
__global__ void label_logit_kernel(const float* __restrict__ inputs,
                                   const int* __restrict__ label,
                                   const float* __restrict__ lut,
                                   const float* __restrict__ cq,
                                   const float* __restrict__ rel,
                                   float* __restrict__ rowlogit) {
  const int lane = threadIdx.x & 63;
  const int wv = threadIdx.x >> 6;
  const int row = blockIdx.x * 4 + wv;
  if (row >= NROWS) return;
  const int l = label[row];
  float out = 0.0f;
  if (l != IGNORE_IDX && l >= 0 && l < LCOLS) {
    const float* bk = (l < NPIDS) ? (lut + (size_t)l * DDIM)
                                  : (cq + (size_t)(l - NPIDS) * DDIM);
    f32x4 a = *(const f32x4*)(inputs + (size_t)row * DDIM + lane * 4);
    f32x4 b = *(const f32x4*)(bk + lane * 4);
    float d = a[0] * b[0] + a[1] * b[1] + a[2] * b[2] + a[3] * b[3];
#pragma unroll
    for (int m = 1; m < 64; m <<= 1) d += __shfl_xor(d, m);
    out = OIM_SCALE * rel[l] * d;
  }
  if (lane == 0) rowlogit[row] = out;
}

// ---------------------------------------------------------------------------
// reduce1: 32 blocks x 256 threads, one row per thread.
// per-row: tot = sum(parts) - PADCOLS; s = ln2*log2(tot) - label_logit.
// ---------------------------------------------------------------------------
__global__ void reduce1_kernel(const float* __restrict__ parts,
                               const float* __restrict__ rowlogit,
                               const int* __restrict__ label,
                               float* __restrict__ blk) {
  const int r = blockIdx.x * 256 + threadIdx.x;
  float s = 0.0f, c = 0.0f;
  if (label[r] != IGNORE_IDX) {
    float tot = 0.0f;
#pragma unroll
    for (int p = 0; p < NPARTS; ++p) tot += parts[p * NROWS + r];
    tot -= (float)PADCOLS;
    s = LN2f * log2f(tot) - rowlogit[r];
    c = 1.0f;
  }
#pragma unroll
  for (int m = 1; m < 64; m <<= 1) {
    s += __shfl_xor(s, m);
    c += __shfl_xor(c, m);
  }
  __shared__ float ss[4], sc[4];
  const int wv = threadIdx.x >> 6, lane = threadIdx.x & 63;
  if (lane == 0) { ss[wv] = s; sc[wv] = c; }
  __syncthreads();
  if (threadIdx.x == 0) {
    blk[blockIdx.x * 2 + 0] = ss[0] + ss[1] + ss[2] + ss[3];
    blk[blockIdx.x * 2 + 1] = sc[0] + sc[1] + sc[2] + sc[3];
  }
}

__global__ void reduce2_kernel(const float* __restrict__ blk,
                               float* __restrict__ out) {
  const int lane = threadIdx.x;
  float s = (lane < 32) ? blk[lane * 2 + 0] : 0.0f;
  float c = (lane < 32) ? blk[lane * 2 + 1] : 0.0f;
#pragma unroll
  for (int m = 1; m < 32; m <<= 1) {
    s += __shfl_xor(s, m);
    c += __shfl_xor(c, m);
  }
  if (lane == 0) out[0] = s / fmaxf(c, 1.0f);
}

extern "C" void kernel_launch(void* const* d_in, const int* in_sizes, int n_in,
                              void* d_out, int out_size, void* d_ws,
                              size_t ws_size, hipStream_t stream) {
  const float* inputs = (const float*)d_in[0];
  const int* label = (const int*)d_in[1];
  // d_in[2] = ious (unused by the reference loss)
  const float* lut = (const float*)d_in[3];
  const float* cq = (const float*)d_in[4];
  const float* rel = (const float*)d_in[5];
  float* out = (float*)d_out;
  char* ws = (char*)d_ws;
  if (ws_size < WS_NEED) return;

  unsigned short* in_bf = (unsigned short*)(ws + WS_INBF);
  unsigned short* bank_swz = (unsigned short*)(ws + WS_BANK);
  float* rse = (float*)(ws + WS_RSE);
  float* parts = (float*)(ws + WS_PARTS);
  float* rowlogit = (float*)(ws + WS_RLOGIT);
  float* blk = (float*)(ws + WS_BLK);

  hipFuncSetAttribute((const void*)oim_main_kernel,
                      hipFuncAttributeMaxDynamicSharedMemorySize, 65536);

  prep_kernel<<<dim3(1024), dim3(256), 0, stream>>>(inputs, lut, cq, rel,
                                                    in_bf, bank_swz, rse);
  oim_main_kernel<<<dim3(64 * NSPLIT), dim3(256), 65536, stream>>>(
      in_bf, bank_swz, rse, parts);
  label_logit_kernel<<<dim3(2048), dim3(256), 0, stream>>>(inputs, label, lut,
                                                           cq, rel, rowlogit);
  reduce1_kernel<<<dim3(32), dim3(256), 0, stream>>>(parts, rowlogit, label,
                                                     blk);
  reduce2_kernel<<<dim3(1), dim3(64), 0, stream>>>(blk, out);
}

// Round 3
// 65.520 us; speedup vs baseline: 1.6315x; 1.3002x over previous
//
#include <hip/hip_runtime.h>
#include <stdint.h>

#define NROWS 8192
#define DDIM 256
#define NPIDS 5532
#define NCQ 5000
#define LCOLS 10532            // NPIDS + NCQ
#define IGNORE_IDX 5554
#define BM 128
#define BN 128
#define NT 83                  // ceil(10532/128)
#define LPAD (NT * BN)         // 10624
#define NSPLIT 8
#define NPARTS (NSPLIT * 2)    // 16 partial slots per row
#define PADCOLS (LPAD - LCOLS) // 92, each contributes exp2(0)=1 exactly
#define OIM_SCALE 30.0f
#define LOG2E 1.4426950408889634f
#define LN2f 0.6931471805599453f

using f32x4 = __attribute__((ext_vector_type(4))) float;
using bf16x8 = __attribute__((ext_vector_type(8))) __bf16;
using ushort8 = __attribute__((ext_vector_type(8))) unsigned short;

// ws layout (bytes)
#define WS_INBF 0u             // 8192*256*2   = 4,194,304 (plain bf16)
#define WS_BANK 4194304u       // 10624*256*2  = 5,439,488 (swizzled, rse-scaled)
#define WS_PARTS 9633792u      // 16*8192*4    = 524,288
#define WS_RLOGIT 10158080u    // 8192*4       = 32,768
#define WS_BLK 10190848u       // 32*2*4       = 256
#define WS_NEED 10191104u

__device__ __forceinline__ unsigned short f2bf(float f) {
  union { float f; uint32_t u; } v; v.f = f;
  uint32_t u = v.u;
  uint32_t r = (u + 0x7FFFu + ((u >> 16) & 1u)) >> 16;  // RNE
  return (unsigned short)r;
}

__device__ __forceinline__ void async16(const void* g, void* l) {
  __builtin_amdgcn_global_load_lds(
      (const __attribute__((address_space(1))) uint32_t*)g,
      (__attribute__((address_space(3))) uint32_t*)l, 16, 0, 0);
}

// ---------------------------------------------------------------------------
// prep: inputs -> plain bf16. bank (lut||cq, zero pad) -> bf16, row j scaled
// by 30*rel[j]*log2e BEFORE quantization (mathematically identical rounding),
// PRE-XOR-SWIZZLED in 16B granules: ws[r][c8] = M[r][c8 ^ (r&7)] so a LINEAR
// global_load_lds lands swizzled. Main-loop epilogue is then pure exp2+add.
// ---------------------------------------------------------------------------
__global__ void prep_kernel(const float* __restrict__ inputs,
                            const float* __restrict__ lut,
                            const float* __restrict__ cq,
                            const float* __restrict__ rel,
                            unsigned short* __restrict__ in_bf,
                            unsigned short* __restrict__ bank_swz) {
  const int GIN = NROWS * (DDIM / 8);   // 262144 granules
  const int GBK = LPAD * (DDIM / 8);    // 339968 granules
  const int total = GIN + GBK;
  for (int g = blockIdx.x * blockDim.x + threadIdx.x; g < total;
       g += gridDim.x * blockDim.x) {
    const float* src = nullptr;
    unsigned short* dst;
    float scale = 1.0f;
    bool zero = false;
    if (g < GIN) {
      const int r = g >> 5, c8 = g & 31;
      src = inputs + r * DDIM + c8 * 8;            // A: no swizzle
      dst = in_bf + r * DDIM + c8 * 8;
    } else {
      const int base = g - GIN;
      const int r = base >> 5, c8 = base & 31;
      const int sc8 = c8 ^ (r & 7);                // B: swizzled source
      dst = bank_swz + r * DDIM + c8 * 8;
      if (r < NPIDS) src = lut + r * DDIM + sc8 * 8;
      else if (r < LCOLS) src = cq + (r - NPIDS) * DDIM + sc8 * 8;
      else zero = true;
      if (!zero) scale = OIM_SCALE * LOG2E * rel[r];
    }
    ushort8 o = {0, 0, 0, 0, 0, 0, 0, 0};
    if (!zero) {
      const f32x4* s4 = (const f32x4*)src;
      f32x4 v0 = s4[0], v1 = s4[1];
      o[0] = f2bf(v0[0] * scale); o[1] = f2bf(v0[1] * scale);
      o[2] = f2bf(v0[2] * scale); o[3] = f2bf(v0[3] * scale);
      o[4] = f2bf(v1[0] * scale); o[5] = f2bf(v1[1] * scale);
      o[6] = f2bf(v1[2] * scale); o[7] = f2bf(v1[3] * scale);
    }
    *(ushort8*)dst = o;
  }
}

// ---------------------------------------------------------------------------
// main: fused GEMM + sum-of-exp per row.
// 512 blocks (2/CU), 256 threads = 4 waves (2x2 over a 128x128 tile).
// sp = blockIdx & 7 == XCD id: each XCD's 64 blocks share one B slice.
// A: per-wave register fragments, loaded once from global.
// B: 4 x 16KB LDS quarter-buffers (K-quarters), staged 3 ahead via
//    global_load_lds; counted `s_waitcnt vmcnt(8)` + raw s_barrier per
//    quarter — loads stay in flight across barriers (no vmcnt(0) drain).
// B rows are pre-scaled by rse -> epilogue is exp2(acc) + add only.
// ---------------------------------------------------------------------------
__global__ __launch_bounds__(256, 2) void oim_main_kernel(
    const unsigned short* __restrict__ in_bf,
    const unsigned short* __restrict__ bank_swz,
    float* __restrict__ parts) {
  extern __shared__ char Bs[];  // 65536 B = 4 x 16KB quarters
  const int tid = threadIdx.x;
  const int lane = tid & 63;
  const int wv = tid >> 6;
  const int wrow = wv >> 1;   // 0..1
  const int wcol = wv & 1;    // 0..1
  const int ql = lane & 15;
  const int h = lane >> 4;    // 0..3

  const int sp = blockIdx.x & 7;
  const int bm = blockIdx.x >> 3;
  const int ntiles = (NT - sp + NSPLIT - 1) / NSPLIT;  // 10 or 11
  const int NQ = ntiles * 4;

  // staging geometry: quarter qq of tile t:
  //   src = bank + t*65536 + qq*128 + (tid>>3)*512 + (tid&7)*16 + j*16384
  //   dst = Bs + qq*16384 + tid*16 + j*4096      (j = 0..3)
  const int dst_lin = tid * 16;
  const int src_row = (tid >> 3) * 512 + (tid & 7) * 16;
  const char* bank0 = (const char*)bank_swz;

  // prologue: stage quarters 0,1,2 of tile 0 (12 loads in flight)
  {
    const char* tb = bank0 + (size_t)sp * 65536;
#pragma unroll
    for (int qq = 0; qq < 3; ++qq)
#pragma unroll
      for (int j = 0; j < 4; ++j)
        async16(tb + qq * 128 + src_row + j * 16384,
                Bs + qq * 16384 + dst_lin + j * 4096);
  }

  // A fragments -> registers (once)
  bf16x8 aR[4][8];
  {
    const unsigned short* ab =
        in_bf + ((size_t)(bm * BM + wrow * 64 + ql) * DDIM + h * 8);
#pragma unroll
    for (int mi = 0; mi < 4; ++mi)
#pragma unroll
      for (int kk = 0; kk < 8; ++kk)
        aR[mi][kk] = *(const bf16x8*)(ab + mi * 16 * DDIM + kk * 32);
  }

  // LDS read lane bases: addr = pX + q*16384 + ni*2048 (imm-foldable, <=65520)
  const int b0off = (wcol * 64 + ql) * 128 + ((h ^ (ql & 7)) << 4);
  const char* p0 = Bs + b0off;
  const char* p1 = Bs + (b0off ^ 64);

  const f32x4 vzero = {0.f, 0.f, 0.f, 0.f};
  f32x4 acc[4][4];
  float se[4][4];
#pragma unroll
  for (int a = 0; a < 4; ++a)
#pragma unroll
    for (int b = 0; b < 4; ++b) se[a][b] = 0.f;

  size_t tb_cur = (size_t)sp * 65536;
  const size_t tb_step = (size_t)NSPLIT * 65536;

  for (int i = 0; i < ntiles; ++i) {
    const char* cb = bank0 + tb_cur;            // current tile base
    const char* nb = cb + tb_step;              // next tile base
    const int Qbase = i * 4;
#pragma unroll
    for (int q = 0; q < 4; ++q) {
      const int Q = Qbase + q;
      const int ahead = NQ - 1 - Q;
      // counted waits: stage(Q) is always >=8 vmem ops older than newest
      if (ahead >= 2)      asm volatile("s_waitcnt vmcnt(8)" ::: "memory");
      else if (ahead == 1) asm volatile("s_waitcnt vmcnt(4)" ::: "memory");
      else                 asm volatile("s_waitcnt vmcnt(0)" ::: "memory");
      asm volatile("s_barrier" ::: "memory");   // raw barrier: no vmcnt drain
      if (Q + 3 < NQ) {  // stage quarter Q+3 into buffer (q+3)&3
        const int qq = (q + 3) & 3;
        const char* sb = (q == 0) ? cb : nb;
#pragma unroll
        for (int j = 0; j < 4; ++j)
          async16(sb + qq * 128 + src_row + j * 16384,
                  Bs + qq * 16384 + dst_lin + j * 4096);
      }
      // compute ksteps 2q, 2q+1 from buffer q
#pragma unroll
      for (int j = 0; j < 2; ++j) {
        const int kk = q * 2 + j;
        const char* bp = j ? p1 : p0;
        bf16x8 bF[4];
#pragma unroll
        for (int ni = 0; ni < 4; ++ni)
          bF[ni] = *(const bf16x8*)(bp + q * 16384 + ni * 2048);
        __builtin_amdgcn_s_setprio(1);
#pragma unroll
        for (int mi = 0; mi < 4; ++mi)
#pragma unroll
          for (int ni = 0; ni < 4; ++ni)
            acc[mi][ni] = __builtin_amdgcn_mfma_f32_16x16x32_bf16(
                aR[mi][kk], bF[ni], (kk == 0) ? vzero : acc[mi][ni], 0, 0, 0);
        __builtin_amdgcn_s_setprio(0);
      }
    }
    // tile epilogue: pure exp2 + add (B pre-scaled by rse; pad cols -> +1.0,
    // corrected by PADCOLS in reduce1)
#pragma unroll
    for (int ni = 0; ni < 4; ++ni)
#pragma unroll
      for (int mi = 0; mi < 4; ++mi)
#pragma unroll
        for (int r = 0; r < 4; ++r)
          se[mi][r] += __builtin_amdgcn_exp2f(acc[mi][ni][r]);
    tb_cur += tb_step;
  }

  // reduce across the 16 column-lanes (ql) of each row group
#pragma unroll
  for (int mi = 0; mi < 4; ++mi)
#pragma unroll
    for (int r = 0; r < 4; ++r) {
      float v = se[mi][r];
      v += __shfl_xor(v, 1);
      v += __shfl_xor(v, 2);
      v += __shfl_xor(v, 4);
      v += __shfl_xor(v, 8);
      se[mi][r] = v;
    }
  if (ql == 0) {
    const int part = sp * 2 + wcol;  // deterministic partial slot
#pragma unroll
    for (int mi = 0; mi < 4; ++mi)
#pragma unroll
      for (int r = 0; r < 4; ++r) {
        const int row = bm * BM + wrow * 64 + mi * 16 + h * 4 + r;
        parts[part * NROWS + row] = se[mi][r];
      }
  }
}

// ---------------------------------------------------------------------------
// exact fp32 label logit: one wave per row, gather bank row by label.
// ---------------------------------------------------------------------------
__global__ void label_logit_kernel(const float* __restrict__ inputs,
                                   const int* __restrict__ label,
                                   const float* __restrict__ lut,
                                   const float* __restrict__ cq,
                                   const float* __restrict__ rel,
                                   float* __restrict__ rowlogit) {
  const int lane = threadIdx.x & 63;
  const int wv = threadIdx.x >> 6;
  const int row = blockIdx.x * 4 + wv;
  if (row >= NROWS) return;
  const int l = label[row];
  float out = 0.0f;
  if (l != IGNORE_IDX && l >= 0 && l < LCOLS) {
    const float* bk = (l < NPIDS) ? (lut + (size_t)l * DDIM)
                                  : (cq + (size_t)(l - NPIDS) * DDIM);
    f32x4 a = *(const f32x4*)(inputs + (size_t)row * DDIM + lane * 4);
    f32x4 b = *(const f32x4*)(bk + lane * 4);
    float d = a[0] * b[0] + a[1] * b[1] + a[2] * b[2] + a[3] * b[3];
#pragma unroll
    for (int m = 1; m < 64; m <<= 1) d += __shfl_xor(d, m);
    out = OIM_SCALE * rel[l] * d;
  }
  if (lane == 0) rowlogit[row] = out;
}

// ---------------------------------------------------------------------------
// reduce1: 32 blocks x 256 threads, one row per thread.
// ---------------------------------------------------------------------------
__global__ void reduce1_kernel(const float* __restrict__ parts,
                               const float* __restrict__ rowlogit,
                               const int* __restrict__ label,
                               float* __restrict__ blk) {
  const int r = blockIdx.x * 256 + threadIdx.x;
  float s = 0.0f, c = 0.0f;
  if (label[r] != IGNORE_IDX) {
    float tot = 0.0f;
#pragma unroll
    for (int p = 0; p < NPARTS; ++p) tot += parts[p * NROWS + r];
    tot -= (float)PADCOLS;
    s = LN2f * log2f(tot) - rowlogit[r];
    c = 1.0f;
  }
#pragma unroll
  for (int m = 1; m < 64; m <<= 1) {
    s += __shfl_xor(s, m);
    c += __shfl_xor(c, m);
  }
  __shared__ float ss[4], sc[4];
  const int wv = threadIdx.x >> 6, lane = threadIdx.x & 63;
  if (lane == 0) { ss[wv] = s; sc[wv] = c; }
  __syncthreads();
  if (threadIdx.x == 0) {
    blk[blockIdx.x * 2 + 0] = ss[0] + ss[1] + ss[2] + ss[3];
    blk[blockIdx.x * 2 + 1] = sc[0] + sc[1] + sc[2] + sc[3];
  }
}

__global__ void reduce2_kernel(const float* __restrict__ blk,
                               float* __restrict__ out) {
  const int lane = threadIdx.x;
  float s = (lane < 32) ? blk[lane * 2 + 0] : 0.0f;
  float c = (lane < 32) ? blk[lane * 2 + 1] : 0.0f;
#pragma unroll
  for (int m = 1; m < 32; m <<= 1) {
    s += __shfl_xor(s, m);
    c += __shfl_xor(c, m);
  }
  if (lane == 0) out[0] = s / fmaxf(c, 1.0f);
}

extern "C" void kernel_launch(void* const* d_in, const int* in_sizes, int n_in,
                              void* d_out, int out_size, void* d_ws,
                              size_t ws_size, hipStream_t stream) {
  const float* inputs = (const float*)d_in[0];
  const int* label = (const int*)d_in[1];
  // d_in[2] = ious (unused by the reference loss)
  const float* lut = (const float*)d_in[3];
  const float* cq = (const float*)d_in[4];
  const float* rel = (const float*)d_in[5];
  float* out = (float*)d_out;
  char* ws = (char*)d_ws;
  if (ws_size < WS_NEED) return;

  unsigned short* in_bf = (unsigned short*)(ws + WS_INBF);
  unsigned short* bank_swz = (unsigned short*)(ws + WS_BANK);
  float* parts = (float*)(ws + WS_PARTS);
  float* rowlogit = (float*)(ws + WS_RLOGIT);
  float* blk = (float*)(ws + WS_BLK);

  hipFuncSetAttribute((const void*)oim_main_kernel,
                      hipFuncAttributeMaxDynamicSharedMemorySize, 65536);

  prep_kernel<<<dim3(1024), dim3(256), 0, stream>>>(inputs, lut, cq, rel,
                                                    in_bf, bank_swz);
  oim_main_kernel<<<dim3(64 * NSPLIT), dim3(256), 65536, stream>>>(
      in_bf, bank_swz, parts);
  label_logit_kernel<<<dim3(2048), dim3(256), 0, stream>>>(inputs, label, lut,
                                                           cq, rel, rowlogit);
  reduce1_kernel<<<dim3(32), dim3(256), 0, stream>>>(parts, rowlogit, label,
                                                     blk);
  reduce2_kernel<<<dim3(1), dim3(64), 0, stream>>>(blk, out);
}